// Round 6
// baseline (1302.496 us; speedup 1.0000x reference)
//
#include <hip/hip_runtime.h>
#include <cstdint>
#include <cstddef>

#define D 1024
#define LSEQ 2048
#define BATCH 8
#define NCHUNK 32   // LSEQ / 64

typedef float fx4  __attribute__((ext_vector_type(4)));
typedef short s16x8 __attribute__((ext_vector_type(8)));
typedef short s16x4 __attribute__((ext_vector_type(4)));

static __device__ __forceinline__ short f2bf(float f) {
  unsigned u = __builtin_bit_cast(unsigned, f);
  u = (u + 0x7FFFu + ((u >> 16) & 1u)) >> 16;   // RNE (finite values)
  return (short)u;
}
static __device__ __forceinline__ float bf2f(unsigned short h) {
  unsigned u = ((unsigned)h) << 16;
  return __builtin_bit_cast(float, u);
}

// ---------------------------------------------------------------------------
// pack fp32 -> bf16 (grid-stride, 8 elems/thread/iter)
// ---------------------------------------------------------------------------
__global__ __launch_bounds__(256)
void pack_bf16(const float* __restrict__ in, short* __restrict__ outp, int n8) {
  int i = blockIdx.x * 256 + threadIdx.x;
  const int stride = gridDim.x * 256;
  for (; i < n8; i += stride) {
    const float* p = in + (size_t)i * 8;
    s16x8 o;
#pragma unroll
    for (int j = 0; j < 8; ++j) o[j] = f2bf(p[j]);
    *(s16x8*)(outp + (size_t)i * 8) = o;
  }
}

// ---------------------------------------------------------------------------
// W [K][N] fp32 -> WT [N][K] bf16, 64x64 tiles via LDS
// ---------------------------------------------------------------------------
__global__ __launch_bounds__(256)
void wtrans(const float* __restrict__ W, short* __restrict__ WT) {
  __shared__ short Tl[64][66];
  const int nt = blockIdx.x, kt0 = blockIdx.y;
  const int tid = threadIdx.x;
  const int c = (tid & 15) * 4, r = tid >> 4;
#pragma unroll
  for (int p = 0; p < 4; ++p) {
    const int krow = r + p * 16;
    float4 v4 = *(const float4*)&W[(size_t)(kt0 * 64 + krow) * D + nt * 64 + c];
    Tl[c + 0][krow] = f2bf(v4.x);
    Tl[c + 1][krow] = f2bf(v4.y);
    Tl[c + 2][krow] = f2bf(v4.z);
    Tl[c + 3][krow] = f2bf(v4.w);
  }
  __syncthreads();
#pragma unroll
  for (int p = 0; p < 4; ++p) {
    const int n = r + p * 16;
    s16x4 o4;
#pragma unroll
    for (int j = 0; j < 4; ++j) o4[j] = Tl[n][c + j];
    *(s16x4*)(WT + (size_t)(nt * 64 + n) * D + kt0 * 64 + c) = o4;
  }
}

// ---------------------------------------------------------------------------
// bf16 MFMA projection GEMM (unchanged from round 3)
// ---------------------------------------------------------------------------
__global__ __launch_bounds__(256)
void proj_mfma(const short* __restrict__ A, const short* __restrict__ Bt,
               short* __restrict__ OUT, int mode, float scale) {
  __shared__ short As[2][4096];
  __shared__ short Bs[2][4096];
  const int tid = threadIdx.x;
  const int l = tid & 63, w = tid >> 6;
  const int lo = l & 15, hi = l >> 4;
  const int wm = w >> 1, wn = w & 1;
  const int row0 = blockIdx.x * 128, col0 = blockIdx.y * 128;

#define STAGE(nb, ktn)                                                          \
  {                                                                             \
    const short* ga0 = A + ((size_t)(row0 + l) * D + (ktn) + w * 8);            \
    const short* gb0 = Bt + ((size_t)(col0 + l) * D + (ktn) + w * 8);           \
    __builtin_amdgcn_global_load_lds(                                           \
        (const __attribute__((address_space(1))) void*)ga0,                     \
        (__attribute__((address_space(3))) void*)&As[nb][(w * 128) * 8], 16, 0, 0); \
    __builtin_amdgcn_global_load_lds(                                           \
        (const __attribute__((address_space(1))) void*)(ga0 + 64 * D),          \
        (__attribute__((address_space(3))) void*)&As[nb][(w * 128 + 64) * 8], 16, 0, 0); \
    __builtin_amdgcn_global_load_lds(                                           \
        (const __attribute__((address_space(1))) void*)gb0,                     \
        (__attribute__((address_space(3))) void*)&Bs[nb][(w * 128) * 8], 16, 0, 0); \
    __builtin_amdgcn_global_load_lds(                                           \
        (const __attribute__((address_space(1))) void*)(gb0 + 64 * D),          \
        (__attribute__((address_space(3))) void*)&Bs[nb][(w * 128 + 64) * 8], 16, 0, 0); \
  }

  fx4 acc[4][4];
#pragma unroll
  for (int i = 0; i < 4; ++i)
#pragma unroll
    for (int j = 0; j < 4; ++j) acc[i][j] = (fx4){0.f, 0.f, 0.f, 0.f};

  STAGE(0, 0);
  __syncthreads();
  int cur = 0;
  for (int kt = 0; kt < D; kt += 32) {
    if (kt + 32 < D) STAGE(cur ^ 1, kt + 32);
    s16x8 af[4], bfr[4];
#pragma unroll
    for (int mt = 0; mt < 4; ++mt)
      af[mt] = *(const s16x8*)&As[cur][(hi * 128 + wm * 64 + mt * 16 + lo) * 8];
#pragma unroll
    for (int nt = 0; nt < 4; ++nt)
      bfr[nt] = *(const s16x8*)&Bs[cur][(hi * 128 + wn * 64 + nt * 16 + lo) * 8];
#pragma unroll
    for (int mt = 0; mt < 4; ++mt)
#pragma unroll
      for (int nt = 0; nt < 4; ++nt)
        acc[mt][nt] = __builtin_amdgcn_mfma_f32_16x16x32_bf16(af[mt], bfr[nt], acc[mt][nt], 0, 0, 0);
    __syncthreads();
    cur ^= 1;
  }
#undef STAGE

#pragma unroll
  for (int mt = 0; mt < 4; ++mt)
#pragma unroll
    for (int nt = 0; nt < 4; ++nt) {
      const size_t rbase = (size_t)(row0 + wm * 64 + mt * 16 + hi * 4);
      const int col = col0 + wn * 64 + nt * 16 + lo;
#pragma unroll
      for (int r = 0; r < 4; ++r) {
        float val = acc[mt][nt][r];
        if (mode == 0) val *= scale;
        else if (mode == 2) val = val / (1.f + expf(-val));
        OUT[(rbase + r) * D + col] = f2bf(val);
      }
    }
}

// ---------------------------------------------------------------------------
// k row L2-normalize, bf16 in place. One wave per row.
// ---------------------------------------------------------------------------
__global__ __launch_bounds__(256)
void knormb(short* __restrict__ kk) {
  const int lane = threadIdx.x & 63;
  const int w = threadIdx.x >> 6;
  const size_t row = (size_t)blockIdx.x * 4 + w;
  s16x8 v0 = *(const s16x8*)&kk[row * D + lane * 8];
  s16x8 v1 = *(const s16x8*)&kk[row * D + 512 + lane * 8];
  float f[16];
  float ss = 0.f;
#pragma unroll
  for (int j = 0; j < 8; ++j) {
    f[j] = bf2f((unsigned short)v0[j]);
    f[8 + j] = bf2f((unsigned short)v1[j]);
  }
#pragma unroll
  for (int j = 0; j < 16; ++j) ss += f[j] * f[j];
#pragma unroll
  for (int d = 1; d < 64; d <<= 1) ss += __shfl_xor(ss, d, 64);
  const float s = 1.f / fmaxf(sqrtf(ss), 1e-12f);
  s16x8 o0, o1;
#pragma unroll
  for (int j = 0; j < 8; ++j) {
    o0[j] = f2bf(f[j] * s);
    o1[j] = f2bf(f[8 + j] * s);
  }
  *(s16x8*)&kk[row * D + lane * 8] = o0;
  *(s16x8*)&kk[row * D + 512 + lane * 8] = o1;
}

// ---------------------------------------------------------------------------
// transpose kh [b][L][D] -> kT [b][D][L] (bf16), 64x64 tiles via LDS
// ---------------------------------------------------------------------------
__global__ __launch_bounds__(256)
void transpose_bf16(const short* __restrict__ kh, short* __restrict__ kT) {
  __shared__ short Tl[64][66];
  const int dt = blockIdx.x, lt = blockIdx.y, b = blockIdx.z;
  const int tid = threadIdx.x;
  const int c = (tid & 15) * 4, r = tid >> 4;
#pragma unroll
  for (int p = 0; p < 4; ++p) {
    const int row = r + p * 16;
    s16x4 v4 = *(const s16x4*)(kh + ((size_t)b * LSEQ + lt * 64 + row) * D + dt * 64 + c);
#pragma unroll
    for (int j = 0; j < 4; ++j) Tl[c + j][row] = v4[j];
  }
  __syncthreads();
#pragma unroll
  for (int p = 0; p < 4; ++p) {
    const int dk = r + p * 16;
    s16x4 o4;
#pragma unroll
    for (int j = 0; j < 4; ++j) o4[j] = Tl[dk][c + j];
    *(s16x4*)(kT + ((size_t)b * D + dt * 64 + dk) * LSEQ + lt * 64 + c) = o4;
  }
}

// ---------------------------------------------------------------------------
// beta[row] = sigmoid( dot(x_row, Wb) ). fp32 exact.
// ---------------------------------------------------------------------------
__global__ __launch_bounds__(256)
void beta_kernel(const float* __restrict__ x, const float* __restrict__ Wb,
                 float* __restrict__ beta) {
  const int lane = threadIdx.x & 63;
  const int w = threadIdx.x >> 6;
  const size_t row = (size_t)blockIdx.x * 4 + w;
  float s = 0.f;
#pragma unroll
  for (int m = 0; m < 4; ++m) {
    float4 xv = *(const float4*)&x[row * D + m * 256 + lane * 4];
    float4 wv = *(const float4*)&Wb[m * 256 + lane * 4];
    s += xv.x * wv.x + xv.y * wv.y + xv.z * wv.z + xv.w * wv.w;
  }
#pragma unroll
  for (int d = 1; d < 64; d <<= 1) s += __shfl_xor(s, d, 64);
  if (lane == 0) beta[row] = 1.f / (1.f + expf(-s));
}

// ---------------------------------------------------------------------------
// Precompute per chunk (b,t): Minv and Tg (unchanged from round 3)
// ---------------------------------------------------------------------------
__global__ __launch_bounds__(256)
void precompute(const short* __restrict__ qh, const short* __restrict__ kh,
                const float* __restrict__ beta,
                short* __restrict__ Mg, short* __restrict__ Tg) {
  __shared__ float Ash[64 * 65];
  __shared__ float Msh[64 * 65];
  const int tid = threadIdx.x, l = tid & 63, w = tid >> 6;
  const int bt = blockIdx.x;
  const int b = bt >> 5, t = bt & 31;
  const int lo = l & 15, hi = l >> 4;
  const size_t rb = (size_t)b * LSEQ + t * 64;

  fx4 aK[4], aQ[4];
#pragma unroll
  for (int n = 0; n < 4; ++n) { aK[n] = (fx4){0,0,0,0}; aQ[n] = (fx4){0,0,0,0}; }

  const short* krow = kh + (rb + w * 16 + lo) * D;
  const short* qrow = qh + (rb + w * 16 + lo) * D;
#pragma unroll 2
  for (int ks = 0; ks < 32; ++ks) {
    s16x8 ak = *(const s16x8*)(krow + ks * 32 + hi * 8);
    s16x8 aq = *(const s16x8*)(qrow + ks * 32 + hi * 8);
#pragma unroll
    for (int n = 0; n < 4; ++n) {
      s16x8 bk = *(const s16x8*)(kh + (rb + n * 16 + lo) * D + ks * 32 + hi * 8);
      aK[n] = __builtin_amdgcn_mfma_f32_16x16x32_bf16(ak, bk, aK[n], 0, 0, 0);
      aQ[n] = __builtin_amdgcn_mfma_f32_16x16x32_bf16(aq, bk, aQ[n], 0, 0, 0);
    }
  }
#pragma unroll
  for (int n = 0; n < 4; ++n) {
#pragma unroll
    for (int r = 0; r < 4; ++r) {
      const int i = w * 16 + hi * 4 + r, s = n * 16 + lo;
      const float bi = beta[rb + i];
      Ash[i * 65 + s] = (s < i) ? bi * aK[n][r] : 0.f;
      Tg[(size_t)bt * 4096 + i * 64 + s] = (s <= i) ? f2bf(aQ[n][r]) : (short)0;
    }
  }
  __syncthreads();
  if (w == 0) {
    Msh[0 * 65 + l] = (l == 0) ? 1.f : 0.f;
    for (int i = 1; i < 64; ++i) {
      float s = 0.f;
      for (int ss = 0; ss < i; ++ss) s += Ash[i * 65 + ss] * Msh[ss * 65 + l];
      Msh[i * 65 + l] = ((i == l) ? 1.f : 0.f) - s;
    }
  }
  __syncthreads();
  {
    const int row = tid >> 2, c0 = (tid & 3) * 16;
    s16x8 o0, o1;
#pragma unroll
    for (int j = 0; j < 8; ++j) o0[j] = f2bf(Msh[row * 65 + c0 + j]);
#pragma unroll
    for (int j = 0; j < 8; ++j) o1[j] = f2bf(Msh[row * 65 + c0 + 8 + j]);
    *(s16x8*)(Mg + (size_t)bt * 4096 + row * 64 + c0) = o0;
    *(s16x8*)(Mg + (size_t)bt * 4096 + row * 64 + c0 + 8) = o1;
  }
}

// ---------------------------------------------------------------------------
// Sequential chunked scan, v4: 16 waves/CU.
// Grid (8 batches, 64 n-slices) = 512 blocks, 512 threads (8 waves) each
// -> 2 blocks/CU, 16 waves/CU (4/SIMD): double the latency-hiding of v2/v3.
// P1/P3 split k in halves across wave pairs: wave w = (mR = w&3, half = w>>2)
// computes its M-tile's partial over k-half; halves combine via fp32 LDS PS.
// P4/P5 split dk 8 ways (S = 8 fx4 = 32 VGPR/lane). Single-buffered SB.
// Role overlap: W4-7 compute P3-half-1 partials while W0-3 do rhs+P2;
// W4-7 start P4 while W0-3 finalize P3. 5 barriers/chunk, all top-level.
// ---------------------------------------------------------------------------
__global__ __launch_bounds__(512, 4)
void scan_chunked(const short* __restrict__ qh, const short* __restrict__ kh,
                  const short* __restrict__ vh, const short* __restrict__ kT,
                  const float* __restrict__ beta,
                  const short* __restrict__ Mg, const short* __restrict__ Tg,
                  float* __restrict__ out) {
  __shared__ short SB[16 * 1024];      // 32 KB  [n=16][dk=1024] bf16, swizzled
  __shared__ short RTs[16 * 64];       // 2 KB   rhs^T [n][c]
  __shared__ short UTs[16 * 64];       // 2 KB   U^T   [n][c]
  __shared__ float PS[4][16][17];      // 4.25 KB cross-half partial sums
  const int tid = threadIdx.x;
  const int l = tid & 63, w = tid >> 6;
  const int lo = l & 15, hi = l >> 4;
  const int b = blockIdx.x, n0 = blockIdx.y * 16;
  const int mR = w & 3;                // M-tile for P1/P2/P3
  const int khalf = w >> 2;            // k-half for P1/P3 partials
  const size_t bL = (size_t)b * LSEQ;
  const int swl = (lo & 7) << 4;
  const int c0 = mR * 16 + hi * 4;     // chunk-local row base

#define SBF(dkbyte) (*(const s16x8*)((const char*)SB + lo * 2048 + ((dkbyte) ^ swl)))
#define RTF(ks)  (*(const s16x8*)((const char*)RTs + lo * 128 + ((((ks) * 32 + hi * 8) * 2) ^ swl)))
#define UTF(ks)  (*(const s16x8*)((const char*)UTs + lo * 128 + ((((ks) * 32 + hi * 8) * 2) ^ swl)))

  fx4 S[8];
#pragma unroll
  for (int mt = 0; mt < 8; ++mt) S[mt] = (fx4){0.f, 0.f, 0.f, 0.f};

  for (int i = tid; i < 16 * 1024 / 2; i += 512) ((int*)SB)[i] = 0;
  __syncthreads();

  for (int t = 0; t < NCHUNK; ++t) {
    const int r0 = t * 64;
    const size_t mtb = ((size_t)(b * NCHUNK + t)) * 4096 + (mR * 16 + lo) * 64;

    // ---- P1 partial: R_h = K_c[M-tile mR, k-half] @ SB[k-half]
    fx4 a0 = (fx4){0.f, 0.f, 0.f, 0.f}, a1 = (fx4){0.f, 0.f, 0.f, 0.f};
    {
      const short* Ak = kh + (bL + r0 + mR * 16 + lo) * D + khalf * 512 + hi * 8;
#pragma unroll
      for (int g = 0; g < 2; ++g) {
        s16x8 f[8];
#pragma unroll
        for (int i = 0; i < 8; ++i) f[i] = *(const s16x8*)(Ak + (g * 8 + i) * 32);
#pragma unroll
        for (int i = 0; i < 8; i += 2) {
          a0 = __builtin_amdgcn_mfma_f32_16x16x32_bf16(
              f[i], SBF((khalf * 512 + (g * 8 + i) * 32 + hi * 8) * 2), a0, 0, 0, 0);
          a1 = __builtin_amdgcn_mfma_f32_16x16x32_bf16(
              f[i + 1], SBF((khalf * 512 + (g * 8 + i + 1) * 32 + hi * 8) * 2), a1, 0, 0, 0);
        }
      }
    }
    a0 = a0 + a1;

    float vv[4], bb[4];
    if (w >= 4) {
#pragma unroll
      for (int r = 0; r < 4; ++r) PS[mR][hi * 4 + r][lo] = a0[r];
    } else {
#pragma unroll
      for (int r = 0; r < 4; ++r) {
        vv[r] = bf2f((unsigned short)vh[(bL + r0 + c0 + r) * D + n0 + lo]);
        bb[r] = beta[bL + r0 + c0 + r];
      }
    }
    __syncthreads();                                   // bar A: PS(P1) ready

    if (w < 4) {
      // combine halves -> rhs -> RT
      s16x4 pk;
#pragma unroll
      for (int r = 0; r < 4; ++r)
        pk[r] = f2bf(bb[r] * (vv[r] - (a0[r] + PS[mR][hi * 4 + r][lo])));
      *(s16x4*)((char*)RTs + lo * 128 + ((c0 * 2) ^ swl)) = pk;
    } else {
      // P3 partial (k-half 1): Q @ SB
      a0 = (fx4){0.f, 0.f, 0.f, 0.f};
      a1 = (fx4){0.f, 0.f, 0.f, 0.f};
      const short* Aq = qh + (bL + r0 + mR * 16 + lo) * D + 512 + hi * 8;
#pragma unroll
      for (int g = 0; g < 2; ++g) {
        s16x8 f[8];
#pragma unroll
        for (int i = 0; i < 8; ++i) f[i] = *(const s16x8*)(Aq + (g * 8 + i) * 32);
#pragma unroll
        for (int i = 0; i < 8; i += 2) {
          a0 = __builtin_amdgcn_mfma_f32_16x16x32_bf16(
              f[i], SBF((512 + (g * 8 + i) * 32 + hi * 8) * 2), a0, 0, 0, 0);
          a1 = __builtin_amdgcn_mfma_f32_16x16x32_bf16(
              f[i + 1], SBF((512 + (g * 8 + i + 1) * 32 + hi * 8) * 2), a1, 0, 0, 0);
        }
      }
      a0 = a0 + a1;
    }
    __syncthreads();                                   // bar B: RT ready, PS free

    if (w < 4) {
      // P2: U = Minv @ rhs
      const s16x8 mg0 = *(const s16x8*)(Mg + mtb + hi * 8);
      const s16x8 mg1 = *(const s16x8*)(Mg + mtb + 32 + hi * 8);
      fx4 u = (fx4){0.f, 0.f, 0.f, 0.f};
      u = __builtin_amdgcn_mfma_f32_16x16x32_bf16(mg0, RTF(0), u, 0, 0, 0);
      u = __builtin_amdgcn_mfma_f32_16x16x32_bf16(mg1, RTF(1), u, 0, 0, 0);
      s16x4 pk;
#pragma unroll
      for (int r = 0; r < 4; ++r) pk[r] = f2bf(u[r]);
      *(s16x4*)((char*)UTs + lo * 128 + ((c0 * 2) ^ swl)) = pk;
    } else {
#pragma unroll
      for (int r = 0; r < 4; ++r) PS[mR][hi * 4 + r][lo] = a0[r];
    }
    __syncthreads();                                   // bar C: UT ready, PS(P3) ready

    const s16x8 bu0 = UTF(0), bu1 = UTF(1);

    if (w < 4) {
      // P3 finalize: tril(QK)@U + Q@SB(k-half 0) + PS(k-half 1) -> out
      const s16x8 tg0 = *(const s16x8*)(Tg + mtb + hi * 8);
      const s16x8 tg1 = *(const s16x8*)(Tg + mtb + 32 + hi * 8);
      fx4 o = (fx4){0.f, 0.f, 0.f, 0.f};
      o = __builtin_amdgcn_mfma_f32_16x16x32_bf16(tg0, bu0, o, 0, 0, 0);
      o = __builtin_amdgcn_mfma_f32_16x16x32_bf16(tg1, bu1, o, 0, 0, 0);
      a1 = (fx4){0.f, 0.f, 0.f, 0.f};
      const short* Aq = qh + (bL + r0 + mR * 16 + lo) * D + hi * 8;
#pragma unroll
      for (int g = 0; g < 2; ++g) {
        s16x8 f[8];
#pragma unroll
        for (int i = 0; i < 8; ++i) f[i] = *(const s16x8*)(Aq + (g * 8 + i) * 32);
#pragma unroll
        for (int i = 0; i < 8; i += 2) {
          o = __builtin_amdgcn_mfma_f32_16x16x32_bf16(
              f[i], SBF(((g * 8 + i) * 32 + hi * 8) * 2), o, 0, 0, 0);
          a1 = __builtin_amdgcn_mfma_f32_16x16x32_bf16(
              f[i + 1], SBF(((g * 8 + i + 1) * 32 + hi * 8) * 2), a1, 0, 0, 0);
        }
      }
      o = o + a1;
#pragma unroll
      for (int r = 0; r < 4; ++r)
        out[(bL + r0 + c0 + r) * D + n0 + lo] = o[r] + PS[mR][hi * 4 + r][lo];
    }

    // ---- P4: S += K_c^T @ U, dk slice w*128 (all 8 waves)
    {
      const short* KTb = kT + ((size_t)b * D + w * 128 + lo) * LSEQ + r0 + hi * 8;
#pragma unroll
      for (int g = 0; g < 2; ++g) {
        s16x8 f[8];
#pragma unroll
        for (int m4 = 0; m4 < 4; ++m4) {
          f[2 * m4]     = *(const s16x8*)(KTb + (size_t)(g * 4 + m4) * 16 * LSEQ);
          f[2 * m4 + 1] = *(const s16x8*)(KTb + (size_t)(g * 4 + m4) * 16 * LSEQ + 32);
        }
#pragma unroll
        for (int m4 = 0; m4 < 4; ++m4) {
          const int idx = g * 4 + m4;
          S[idx] = __builtin_amdgcn_mfma_f32_16x16x32_bf16(f[2 * m4],     bu0, S[idx], 0, 0, 0);
          S[idx] = __builtin_amdgcn_mfma_f32_16x16x32_bf16(f[2 * m4 + 1], bu1, S[idx], 0, 0, 0);
        }
      }
    }
    __syncthreads();                                   // bar D: all SB/UT/PS reads done

    // ---- P5: SB = bf16(S), own dk slice
#pragma unroll
    for (int mt = 0; mt < 8; ++mt) {
      const int dk0 = w * 128 + mt * 16 + hi * 4;
      s16x4 pk;
#pragma unroll
      for (int r = 0; r < 4; ++r) pk[r] = f2bf(S[mt][r]);
      *(s16x4*)((char*)SB + lo * 2048 + ((dk0 * 2) ^ swl)) = pk;
    }
    __syncthreads();                                   // bar E: new SB ready
  }
#undef SBF
#undef RTF
#undef UTF
}

// ---------------------------------------------------------------------------
// LayerNorm in place on out. One wave per row.
// ---------------------------------------------------------------------------
__global__ __launch_bounds__(256)
void ln_kernel(float* __restrict__ o, const float* __restrict__ gamma,
               const float* __restrict__ betap) {
  const int lane = threadIdx.x & 63;
  const int w = threadIdx.x >> 6;
  const size_t row = (size_t)blockIdx.x * 4 + w;
  float4 vals[4];
  float s = 0.f;
#pragma unroll
  for (int m = 0; m < 4; ++m) {
    vals[m] = *(const float4*)&o[row * D + m * 256 + lane * 4];
    s += (vals[m].x + vals[m].y) + (vals[m].z + vals[m].w);
  }
#pragma unroll
  for (int d = 1; d < 64; d <<= 1) s += __shfl_xor(s, d, 64);
  const float mu = s * (1.f / 1024.f);
  float vs = 0.f;
#pragma unroll
  for (int m = 0; m < 4; ++m) {
    float dx = vals[m].x - mu; vs += dx * dx;
    dx = vals[m].y - mu; vs += dx * dx;
    dx = vals[m].z - mu; vs += dx * dx;
    dx = vals[m].w - mu; vs += dx * dx;
  }
#pragma unroll
  for (int d = 1; d < 64; d <<= 1) vs += __shfl_xor(vs, d, 64);
  const float r = 1.f / sqrtf(vs * (1.f / 1024.f) + 1e-5f);
#pragma unroll
  for (int m = 0; m < 4; ++m) {
    const int dbase = m * 256 + lane * 4;
    float4 g4 = *(const float4*)&gamma[dbase];
    float4 b4 = *(const float4*)&betap[dbase];
    float4 y;
    y.x = (vals[m].x - mu) * r * g4.x + b4.x;
    y.y = (vals[m].y - mu) * r * g4.y + b4.y;
    y.z = (vals[m].z - mu) * r * g4.z + b4.z;
    y.w = (vals[m].w - mu) * r * g4.w + b4.w;
    *(float4*)&o[row * D + dbase] = y;
  }
}

// ---------------------------------------------------------------------------
extern "C" void kernel_launch(void* const* d_in, const int* in_sizes, int n_in,
                              void* d_out, int out_size, void* d_ws, size_t ws_size,
                              hipStream_t stream) {
  const float* x   = (const float*)d_in[0];
  const float* Wq  = (const float*)d_in[1];
  const float* Wk  = (const float*)d_in[2];
  const float* Wv  = (const float*)d_in[3];
  const float* Wb  = (const float*)d_in[4];
  const float* lng = (const float*)d_in[5];
  const float* lnb = (const float*)d_in[6];
  float* out = (float*)d_out;

  const size_t MB = 1ull << 20;
  char* wsb = (char*)d_ws;
  float* beta = (float*)wsb;                 // 64 KB
  short* Mg   = (short*)(wsb + 1 * MB);      // 2 MB
  short* Tg   = (short*)(wsb + 4 * MB);      // 2 MB
  short* WTq  = (short*)(wsb + 6 * MB);      // 2 MB
  short* WTk  = (short*)(wsb + 8 * MB);      // 2 MB
  short* WTv  = (short*)(wsb + 10 * MB);     // 2 MB
  short* xh   = (short*)(wsb + 16 * MB);     // 32 MB
  short* qh   = (short*)(wsb + 64 * MB);     // 32 MB
  short* kh   = (short*)(wsb + 96 * MB);
  short* vh   = (short*)(wsb + 128 * MB);
  short* kT   = (short*)(wsb + 160 * MB);

  const int N8 = (BATCH * LSEQ * D) / 8;
  const dim3 pg(128, 8);

  pack_bf16<<<2048, 256, 0, stream>>>(x, xh, N8);
  wtrans<<<dim3(16, 16), 256, 0, stream>>>(Wq, WTq);
  wtrans<<<dim3(16, 16), 256, 0, stream>>>(Wk, WTk);
  wtrans<<<dim3(16, 16), 256, 0, stream>>>(Wv, WTv);

  proj_mfma<<<pg, 256, 0, stream>>>(xh, WTq, qh, 0, 0.03125f);
  proj_mfma<<<pg, 256, 0, stream>>>(xh, WTk, kh, 1, 1.f);
  proj_mfma<<<pg, 256, 0, stream>>>(xh, WTv, vh, 2, 1.f);

  knormb<<<4096, 256, 0, stream>>>(kh);
  transpose_bf16<<<dim3(16, 32, 8), 256, 0, stream>>>(kh, kT);
  beta_kernel<<<4096, 256, 0, stream>>>(x, Wb, beta);

  precompute<<<256, 256, 0, stream>>>(qh, kh, beta, Mg, Tg);
  scan_chunked<<<dim3(8, 64), 512, 0, stream>>>(qh, kh, vh, kT, beta, Mg, Tg, out);
  ln_kernel<<<4096, 256, 0, stream>>>(out, lng, lnb);
}

// Round 8
// 703.113 us; speedup vs baseline: 1.8525x; 1.8525x over previous
//
#include <hip/hip_runtime.h>
#include <cstdint>
#include <cstddef>

#define D 1024
#define LSEQ 2048
#define BATCH 8
#define NCHUNK 32   // LSEQ / 64

typedef float fx4  __attribute__((ext_vector_type(4)));
typedef short s16x8 __attribute__((ext_vector_type(8)));
typedef short s16x4 __attribute__((ext_vector_type(4)));

static __device__ __forceinline__ short f2bf(float f) {
  unsigned u = __builtin_bit_cast(unsigned, f);
  u = (u + 0x7FFFu + ((u >> 16) & 1u)) >> 16;   // RNE (finite values)
  return (short)u;
}
static __device__ __forceinline__ float bf2f(unsigned short h) {
  unsigned u = ((unsigned)h) << 16;
  return __builtin_bit_cast(float, u);
}

// ---------------------------------------------------------------------------
// pack fp32 -> bf16 (grid-stride, 8 elems/thread/iter)
// ---------------------------------------------------------------------------
__global__ __launch_bounds__(256)
void pack_bf16(const float* __restrict__ in, short* __restrict__ outp, int n8) {
  int i = blockIdx.x * 256 + threadIdx.x;
  const int stride = gridDim.x * 256;
  for (; i < n8; i += stride) {
    const float* p = in + (size_t)i * 8;
    s16x8 o;
#pragma unroll
    for (int j = 0; j < 8; ++j) o[j] = f2bf(p[j]);
    *(s16x8*)(outp + (size_t)i * 8) = o;
  }
}

// ---------------------------------------------------------------------------
// W [K][N] fp32 -> WT [N][K] bf16, 64x64 tiles via LDS
// ---------------------------------------------------------------------------
__global__ __launch_bounds__(256)
void wtrans(const float* __restrict__ W, short* __restrict__ WT) {
  __shared__ short Tl[64][66];
  const int nt = blockIdx.x, kt0 = blockIdx.y;
  const int tid = threadIdx.x;
  const int c = (tid & 15) * 4, r = tid >> 4;
#pragma unroll
  for (int p = 0; p < 4; ++p) {
    const int krow = r + p * 16;
    float4 v4 = *(const float4*)&W[(size_t)(kt0 * 64 + krow) * D + nt * 64 + c];
    Tl[c + 0][krow] = f2bf(v4.x);
    Tl[c + 1][krow] = f2bf(v4.y);
    Tl[c + 2][krow] = f2bf(v4.z);
    Tl[c + 3][krow] = f2bf(v4.w);
  }
  __syncthreads();
#pragma unroll
  for (int p = 0; p < 4; ++p) {
    const int n = r + p * 16;
    s16x4 o4;
#pragma unroll
    for (int j = 0; j < 4; ++j) o4[j] = Tl[n][c + j];
    *(s16x4*)(WT + (size_t)(nt * 64 + n) * D + kt0 * 64 + c) = o4;
  }
}

// ---------------------------------------------------------------------------
// bf16 MFMA projection GEMM (unchanged from round 3)
// ---------------------------------------------------------------------------
__global__ __launch_bounds__(256)
void proj_mfma(const short* __restrict__ A, const short* __restrict__ Bt,
               short* __restrict__ OUT, int mode, float scale) {
  __shared__ short As[2][4096];
  __shared__ short Bs[2][4096];
  const int tid = threadIdx.x;
  const int l = tid & 63, w = tid >> 6;
  const int lo = l & 15, hi = l >> 4;
  const int wm = w >> 1, wn = w & 1;
  const int row0 = blockIdx.x * 128, col0 = blockIdx.y * 128;

#define STAGE(nb, ktn)                                                          \
  {                                                                             \
    const short* ga0 = A + ((size_t)(row0 + l) * D + (ktn) + w * 8);            \
    const short* gb0 = Bt + ((size_t)(col0 + l) * D + (ktn) + w * 8);           \
    __builtin_amdgcn_global_load_lds(                                           \
        (const __attribute__((address_space(1))) void*)ga0,                     \
        (__attribute__((address_space(3))) void*)&As[nb][(w * 128) * 8], 16, 0, 0); \
    __builtin_amdgcn_global_load_lds(                                           \
        (const __attribute__((address_space(1))) void*)(ga0 + 64 * D),          \
        (__attribute__((address_space(3))) void*)&As[nb][(w * 128 + 64) * 8], 16, 0, 0); \
    __builtin_amdgcn_global_load_lds(                                           \
        (const __attribute__((address_space(1))) void*)gb0,                     \
        (__attribute__((address_space(3))) void*)&Bs[nb][(w * 128) * 8], 16, 0, 0); \
    __builtin_amdgcn_global_load_lds(                                           \
        (const __attribute__((address_space(1))) void*)(gb0 + 64 * D),          \
        (__attribute__((address_space(3))) void*)&Bs[nb][(w * 128 + 64) * 8], 16, 0, 0); \
  }

  fx4 acc[4][4];
#pragma unroll
  for (int i = 0; i < 4; ++i)
#pragma unroll
    for (int j = 0; j < 4; ++j) acc[i][j] = (fx4){0.f, 0.f, 0.f, 0.f};

  STAGE(0, 0);
  __syncthreads();
  int cur = 0;
  for (int kt = 0; kt < D; kt += 32) {
    if (kt + 32 < D) STAGE(cur ^ 1, kt + 32);
    s16x8 af[4], bfr[4];
#pragma unroll
    for (int mt = 0; mt < 4; ++mt)
      af[mt] = *(const s16x8*)&As[cur][(hi * 128 + wm * 64 + mt * 16 + lo) * 8];
#pragma unroll
    for (int nt = 0; nt < 4; ++nt)
      bfr[nt] = *(const s16x8*)&Bs[cur][(hi * 128 + wn * 64 + nt * 16 + lo) * 8];
#pragma unroll
    for (int mt = 0; mt < 4; ++mt)
#pragma unroll
      for (int nt = 0; nt < 4; ++nt)
        acc[mt][nt] = __builtin_amdgcn_mfma_f32_16x16x32_bf16(af[mt], bfr[nt], acc[mt][nt], 0, 0, 0);
    __syncthreads();
    cur ^= 1;
  }
#undef STAGE

#pragma unroll
  for (int mt = 0; mt < 4; ++mt)
#pragma unroll
    for (int nt = 0; nt < 4; ++nt) {
      const size_t rbase = (size_t)(row0 + wm * 64 + mt * 16 + hi * 4);
      const int col = col0 + wn * 64 + nt * 16 + lo;
#pragma unroll
      for (int r = 0; r < 4; ++r) {
        float val = acc[mt][nt][r];
        if (mode == 0) val *= scale;
        else if (mode == 2) val = val / (1.f + expf(-val));
        OUT[(rbase + r) * D + col] = f2bf(val);
      }
    }
}

// ---------------------------------------------------------------------------
// k row L2-normalize, bf16 in place. One wave per row.
// ---------------------------------------------------------------------------
__global__ __launch_bounds__(256)
void knormb(short* __restrict__ kk) {
  const int lane = threadIdx.x & 63;
  const int w = threadIdx.x >> 6;
  const size_t row = (size_t)blockIdx.x * 4 + w;
  s16x8 v0 = *(const s16x8*)&kk[row * D + lane * 8];
  s16x8 v1 = *(const s16x8*)&kk[row * D + 512 + lane * 8];
  float f[16];
  float ss = 0.f;
#pragma unroll
  for (int j = 0; j < 8; ++j) {
    f[j] = bf2f((unsigned short)v0[j]);
    f[8 + j] = bf2f((unsigned short)v1[j]);
  }
#pragma unroll
  for (int j = 0; j < 16; ++j) ss += f[j] * f[j];
#pragma unroll
  for (int d = 1; d < 64; d <<= 1) ss += __shfl_xor(ss, d, 64);
  const float s = 1.f / fmaxf(sqrtf(ss), 1e-12f);
  s16x8 o0, o1;
#pragma unroll
  for (int j = 0; j < 8; ++j) {
    o0[j] = f2bf(f[j] * s);
    o1[j] = f2bf(f[8 + j] * s);
  }
  *(s16x8*)&kk[row * D + lane * 8] = o0;
  *(s16x8*)&kk[row * D + 512 + lane * 8] = o1;
}

// ---------------------------------------------------------------------------
// transpose kh [b][L][D] -> kT [b][D][L] (bf16), 64x64 tiles via LDS
// ---------------------------------------------------------------------------
__global__ __launch_bounds__(256)
void transpose_bf16(const short* __restrict__ kh, short* __restrict__ kT) {
  __shared__ short Tl[64][66];
  const int dt = blockIdx.x, lt = blockIdx.y, b = blockIdx.z;
  const int tid = threadIdx.x;
  const int c = (tid & 15) * 4, r = tid >> 4;
#pragma unroll
  for (int p = 0; p < 4; ++p) {
    const int row = r + p * 16;
    s16x4 v4 = *(const s16x4*)(kh + ((size_t)b * LSEQ + lt * 64 + row) * D + dt * 64 + c);
#pragma unroll
    for (int j = 0; j < 4; ++j) Tl[c + j][row] = v4[j];
  }
  __syncthreads();
#pragma unroll
  for (int p = 0; p < 4; ++p) {
    const int dk = r + p * 16;
    s16x4 o4;
#pragma unroll
    for (int j = 0; j < 4; ++j) o4[j] = Tl[dk][c + j];
    *(s16x4*)(kT + ((size_t)b * D + dt * 64 + dk) * LSEQ + lt * 64 + c) = o4;
  }
}

// ---------------------------------------------------------------------------
// beta[row] = sigmoid( dot(x_row, Wb) ). fp32 exact.
// ---------------------------------------------------------------------------
__global__ __launch_bounds__(256)
void beta_kernel(const float* __restrict__ x, const float* __restrict__ Wb,
                 float* __restrict__ beta) {
  const int lane = threadIdx.x & 63;
  const int w = threadIdx.x >> 6;
  const size_t row = (size_t)blockIdx.x * 4 + w;
  float s = 0.f;
#pragma unroll
  for (int m = 0; m < 4; ++m) {
    float4 xv = *(const float4*)&x[row * D + m * 256 + lane * 4];
    float4 wv = *(const float4*)&Wb[m * 256 + lane * 4];
    s += xv.x * wv.x + xv.y * wv.y + xv.z * wv.z + xv.w * wv.w;
  }
#pragma unroll
  for (int d = 1; d < 64; d <<= 1) s += __shfl_xor(s, d, 64);
  if (lane == 0) beta[row] = 1.f / (1.f + expf(-s));
}

// ---------------------------------------------------------------------------
// Precompute per chunk (b,t): Minv and Tg (unchanged from round 3)
// ---------------------------------------------------------------------------
__global__ __launch_bounds__(256)
void precompute(const short* __restrict__ qh, const short* __restrict__ kh,
                const float* __restrict__ beta,
                short* __restrict__ Mg, short* __restrict__ Tg) {
  __shared__ float Ash[64 * 65];
  __shared__ float Msh[64 * 65];
  const int tid = threadIdx.x, l = tid & 63, w = tid >> 6;
  const int bt = blockIdx.x;
  const int b = bt >> 5, t = bt & 31;
  const int lo = l & 15, hi = l >> 4;
  const size_t rb = (size_t)b * LSEQ + t * 64;

  fx4 aK[4], aQ[4];
#pragma unroll
  for (int n = 0; n < 4; ++n) { aK[n] = (fx4){0,0,0,0}; aQ[n] = (fx4){0,0,0,0}; }

  const short* krow = kh + (rb + w * 16 + lo) * D;
  const short* qrow = qh + (rb + w * 16 + lo) * D;
#pragma unroll 2
  for (int ks = 0; ks < 32; ++ks) {
    s16x8 ak = *(const s16x8*)(krow + ks * 32 + hi * 8);
    s16x8 aq = *(const s16x8*)(qrow + ks * 32 + hi * 8);
#pragma unroll
    for (int n = 0; n < 4; ++n) {
      s16x8 bk = *(const s16x8*)(kh + (rb + n * 16 + lo) * D + ks * 32 + hi * 8);
      aK[n] = __builtin_amdgcn_mfma_f32_16x16x32_bf16(ak, bk, aK[n], 0, 0, 0);
      aQ[n] = __builtin_amdgcn_mfma_f32_16x16x32_bf16(aq, bk, aQ[n], 0, 0, 0);
    }
  }
#pragma unroll
  for (int n = 0; n < 4; ++n) {
#pragma unroll
    for (int r = 0; r < 4; ++r) {
      const int i = w * 16 + hi * 4 + r, s = n * 16 + lo;
      const float bi = beta[rb + i];
      Ash[i * 65 + s] = (s < i) ? bi * aK[n][r] : 0.f;
      Tg[(size_t)bt * 4096 + i * 64 + s] = (s <= i) ? f2bf(aQ[n][r]) : (short)0;
    }
  }
  __syncthreads();
  if (w == 0) {
    Msh[0 * 65 + l] = (l == 0) ? 1.f : 0.f;
    for (int i = 1; i < 64; ++i) {
      float s = 0.f;
      for (int ss = 0; ss < i; ++ss) s += Ash[i * 65 + ss] * Msh[ss * 65 + l];
      Msh[i * 65 + l] = ((i == l) ? 1.f : 0.f) - s;
    }
  }
  __syncthreads();
  {
    const int row = tid >> 2, c0 = (tid & 3) * 16;
    s16x8 o0, o1;
#pragma unroll
    for (int j = 0; j < 8; ++j) o0[j] = f2bf(Msh[row * 65 + c0 + j]);
#pragma unroll
    for (int j = 0; j < 8; ++j) o1[j] = f2bf(Msh[row * 65 + c0 + 8 + j]);
    *(s16x8*)(Mg + (size_t)bt * 4096 + row * 64 + c0) = o0;
    *(s16x8*)(Mg + (size_t)bt * 4096 + row * 64 + c0 + 8) = o1;
  }
}

// ---------------------------------------------------------------------------
// Sequential chunked scan, v6: LDS ring staging, codegen-invariant waits.
// v5's bug: WAITV(16) hard-coded the count of "extras" VMEM instructions; the
// compiler merged the 4 beta loads into one dwordx4 so the count was wrong and
// the wait released before the K-slice DMA landed (absmax 0.75). v6: extras
// are issued BEFORE the K0/K1 staging (prologue for t=0, top of P4 for t+1),
// so for every slice the only NEWER vmcnt events are the next slice's 4 DMA
// ops -> uniform s_waitcnt vmcnt(4), independent of codegen. lgkmcnt(0) fence
// before each in-loop re-STAGE closes the ds_read/DMA anti-dependency window.
// ---------------------------------------------------------------------------
__global__ __launch_bounds__(256, 2)
void scan_chunked(const short* __restrict__ qh, const short* __restrict__ kh,
                  const short* __restrict__ vh, const short* __restrict__ kT,
                  const float* __restrict__ beta,
                  const short* __restrict__ Mg, const short* __restrict__ Tg,
                  float* __restrict__ out) {
  __shared__ __align__(16) short SB[16 * 1024];   // 32 KB [n=16][dk] swizzled
  __shared__ __align__(16) short RTs[16 * 64];    // 2 KB rhs^T
  __shared__ __align__(16) short UTs[16 * 64];    // 2 KB U^T
  __shared__ __align__(1024) char RING[4][2][4096];  // 32 KB per-wave rings
  const int tid = threadIdx.x;
  const int l = tid & 63, w = tid >> 6;
  const int lo = l & 15, hi = l >> 4;
  const int b = blockIdx.x, n0 = blockIdx.y * 16;
  const size_t bL = (size_t)b * LSEQ;
  const int swl = (lo & 7) << 4;
  const int c0 = w * 16 + hi * 4;

#define WAITV4() asm volatile("s_waitcnt vmcnt(4)" ::: "memory")
#define LGKM0()  asm volatile("s_waitcnt lgkmcnt(0)" ::: "memory")
#define CFENCE() asm volatile("" ::: "memory")

#define STAGE_KQ(PTR, slot, rowbase, dk0)                                       \
  {                                                                             \
    _Pragma("unroll")                                                           \
    for (int ii = 0; ii < 4; ++ii) {                                            \
      const int rr_ = ii * 4 + (l >> 4);                                        \
      const short* src_ = (PTR) + (bL + (size_t)((rowbase) + rr_)) * D + (dk0)  \
                          + 8 * ((l & 15) ^ (rr_ & 7));                         \
      __builtin_amdgcn_global_load_lds(                                         \
          (const __attribute__((address_space(1))) void*)src_,                  \
          (__attribute__((address_space(3))) void*)&RING[w][slot][ii * 1024],   \
          16, 0, 0);                                                            \
    }                                                                           \
  }

#define STAGE_KT(slot, dkbase, cols)                                            \
  {                                                                             \
    _Pragma("unroll")                                                           \
    for (int ii = 0; ii < 4; ++ii) {                                            \
      const int rr_ = ii * 8 + (l >> 3);                                        \
      const short* src_ = kT + ((size_t)b * D + (dkbase) + rr_) * LSEQ + (cols) \
                          + 8 * ((l & 7) ^ (rr_ & 7));                          \
      __builtin_amdgcn_global_load_lds(                                         \
          (const __attribute__((address_space(1))) void*)src_,                  \
          (__attribute__((address_space(3))) void*)&RING[w][slot][ii * 1024],   \
          16, 0, 0);                                                            \
    }                                                                           \
  }

#define RKQ(slot, ks) \
  (*(const s16x8*)&RING[w][slot][lo * 256 + (((ks) * 64 + hi * 16) ^ swl)])
#define RKT(slot, mt, ksl) \
  (*(const s16x8*)&RING[w][slot][((mt) * 16 + lo) * 128 + (((ksl) * 64 + hi * 16) ^ swl)])
#define SBF(dkbyte) (*(const s16x8*)((const char*)SB + lo * 2048 + ((dkbyte) ^ swl)))
#define RTF(ks) (*(const s16x8*)((const char*)RTs + lo * 128 + ((((ks) * 32 + hi * 8) * 2) ^ swl)))
#define UTF(ks) (*(const s16x8*)((const char*)UTs + lo * 128 + ((((ks) * 32 + hi * 8) * 2) ^ swl)))

  // per-chunk small operands, loaded one chunk ahead of use
  float vv[4], bb[4];
  s16x8 mg0, mg1, tg0, tg1;
#define LOAD_EXTRAS(tt)                                                         \
  {                                                                             \
    const int r0_ = (tt) * 64;                                                  \
    const size_t mtb_ = ((size_t)(b * NCHUNK + (tt))) * 4096 + (w * 16 + lo) * 64; \
    _Pragma("unroll")                                                           \
    for (int r = 0; r < 4; ++r) {                                               \
      vv[r] = bf2f((unsigned short)vh[(bL + r0_ + c0 + r) * D + n0 + lo]);      \
      bb[r] = beta[bL + r0_ + c0 + r];                                          \
    }                                                                           \
    mg0 = *(const s16x8*)(Mg + mtb_ + hi * 8);                                  \
    mg1 = *(const s16x8*)(Mg + mtb_ + 32 + hi * 8);                             \
    tg0 = *(const s16x8*)(Tg + mtb_ + hi * 8);                                  \
    tg1 = *(const s16x8*)(Tg + mtb_ + 32 + hi * 8);                             \
  }

  fx4 S[16];
#pragma unroll
  for (int mt = 0; mt < 16; ++mt) S[mt] = (fx4){0.f, 0.f, 0.f, 0.f};

  for (int i = tid; i < 16 * 1024 / 2; i += 256) ((int*)SB)[i] = 0;

  // prologue: extras(t=0) FIRST (older than staging in vmcnt order), then
  // chunk-0 K slices 0,1 in flight.
  LOAD_EXTRAS(0);
  CFENCE();
  STAGE_KQ(kh, 0, 0 * 64 + w * 16, 0);
  STAGE_KQ(kh, 1, 0 * 64 + w * 16, 128);
  LGKM0();
  __builtin_amdgcn_s_barrier();   // SB zeros visible (no vmcnt drain)

  for (int t = 0; t < NCHUNK; ++t) {
    const int r0 = t * 64;

    // ---- P1: R = K_c @ S  (A from ring, B from SB)
    fx4 a0 = (fx4){0.f, 0.f, 0.f, 0.f}, a1 = (fx4){0.f, 0.f, 0.f, 0.f};
#pragma unroll
    for (int s = 0; s < 8; ++s) {
      WAITV4();
      s16x8 f0 = RKQ(s & 1, 0), f1 = RKQ(s & 1, 1);
      s16x8 f2 = RKQ(s & 1, 2), f3 = RKQ(s & 1, 3);
      a0 = __builtin_amdgcn_mfma_f32_16x16x32_bf16(f0, SBF(s * 256 + 0 + hi * 16), a0, 0, 0, 0);
      a1 = __builtin_amdgcn_mfma_f32_16x16x32_bf16(f1, SBF(s * 256 + 64 + hi * 16), a1, 0, 0, 0);
      a0 = __builtin_amdgcn_mfma_f32_16x16x32_bf16(f2, SBF(s * 256 + 128 + hi * 16), a0, 0, 0, 0);
      a1 = __builtin_amdgcn_mfma_f32_16x16x32_bf16(f3, SBF(s * 256 + 192 + hi * 16), a1, 0, 0, 0);
      LGKM0();   // ring ds_reads retired before the slot is re-staged
      if (s < 6) { STAGE_KQ(kh, s & 1, r0 + w * 16, (s + 2) * 128); }
      else       { STAGE_KQ(qh, s & 1, r0 + w * 16, (s - 6) * 128); }
    }
    {
      const fx4 acc = a0 + a1;
      s16x4 pk;
#pragma unroll
      for (int r = 0; r < 4; ++r) pk[r] = f2bf(bb[r] * (vv[r] - acc[r]));
      *(s16x4*)((char*)RTs + lo * 128 + ((c0 * 2) ^ swl)) = pk;
    }
    LGKM0();
    __builtin_amdgcn_s_barrier();   // bar1: RT ready

    // ---- P2: U = Minv @ rhs
    {
      fx4 u = (fx4){0.f, 0.f, 0.f, 0.f};
      u = __builtin_amdgcn_mfma_f32_16x16x32_bf16(mg0, RTF(0), u, 0, 0, 0);
      u = __builtin_amdgcn_mfma_f32_16x16x32_bf16(mg1, RTF(1), u, 0, 0, 0);
      s16x4 pk;
#pragma unroll
      for (int r = 0; r < 4; ++r) pk[r] = f2bf(u[r]);
      *(s16x4*)((char*)UTs + lo * 128 + ((c0 * 2) ^ swl)) = pk;
    }
    LGKM0();
    __builtin_amdgcn_s_barrier();   // bar2: UT ready

    const s16x8 bu0 = UTF(0), bu1 = UTF(1);

    // ---- P3: O = tril(QK^T) @ U + Q_c @ S(old)
    {
      fx4 o = (fx4){0.f, 0.f, 0.f, 0.f};
      o = __builtin_amdgcn_mfma_f32_16x16x32_bf16(tg0, bu0, o, 0, 0, 0);
      o = __builtin_amdgcn_mfma_f32_16x16x32_bf16(tg1, bu1, o, 0, 0, 0);
      a0 = (fx4){0.f, 0.f, 0.f, 0.f};
#pragma unroll
      for (int s = 0; s < 8; ++s) {
        WAITV4();
        s16x8 f0 = RKQ(s & 1, 0), f1 = RKQ(s & 1, 1);
        s16x8 f2 = RKQ(s & 1, 2), f3 = RKQ(s & 1, 3);
        o  = __builtin_amdgcn_mfma_f32_16x16x32_bf16(f0, SBF(s * 256 + 0 + hi * 16), o, 0, 0, 0);
        a0 = __builtin_amdgcn_mfma_f32_16x16x32_bf16(f1, SBF(s * 256 + 64 + hi * 16), a0, 0, 0, 0);
        o  = __builtin_amdgcn_mfma_f32_16x16x32_bf16(f2, SBF(s * 256 + 128 + hi * 16), o, 0, 0, 0);
        a0 = __builtin_amdgcn_mfma_f32_16x16x32_bf16(f3, SBF(s * 256 + 192 + hi * 16), a0, 0, 0, 0);
        LGKM0();
        if (s < 6) { STAGE_KQ(qh, s & 1, r0 + w * 16, (s + 2) * 128); }
        else       { STAGE_KT(s & 1, w * 256 + (s - 6) * 32, r0); }
      }
      o = o + a0;
#pragma unroll
      for (int r = 0; r < 4; ++r)
        out[(bL + r0 + c0 + r) * D + n0 + lo] = o[r];
    }
    LGKM0();
    __builtin_amdgcn_s_barrier();   // bar3: all SB reads retired

    // ---- extras for chunk t+1: issued BEFORE next-chunk K staging so the
    // uniform vmcnt(4) stays exact (they are older than every staged slice).
    {
      const int tn = (t + 1 < NCHUNK) ? (t + 1) : (NCHUNK - 1);
      LOAD_EXTRAS(tn);
    }

    // ---- P4: S += K_c^T @ U  (A from ring kT slices)
#pragma unroll
    for (int s = 0; s < 8; ++s) {
      WAITV4();
      s16x8 g0 = RKT(s & 1, 0, 0), g1 = RKT(s & 1, 0, 1);
      s16x8 g2 = RKT(s & 1, 1, 0), g3 = RKT(s & 1, 1, 1);
      S[2 * s]     = __builtin_amdgcn_mfma_f32_16x16x32_bf16(g0, bu0, S[2 * s], 0, 0, 0);
      S[2 * s]     = __builtin_amdgcn_mfma_f32_16x16x32_bf16(g1, bu1, S[2 * s], 0, 0, 0);
      S[2 * s + 1] = __builtin_amdgcn_mfma_f32_16x16x32_bf16(g2, bu0, S[2 * s + 1], 0, 0, 0);
      S[2 * s + 1] = __builtin_amdgcn_mfma_f32_16x16x32_bf16(g3, bu1, S[2 * s + 1], 0, 0, 0);
      LGKM0();
      if (s < 6) { STAGE_KT(s & 1, w * 256 + (s + 2) * 32, r0); }
      else if (t + 1 < NCHUNK) {
        STAGE_KQ(kh, s & 1, r0 + 64 + w * 16, (s - 6) * 128);
      }
    }

    // ---- P5: SB = bf16(S), own dk slice
#pragma unroll
    for (int mt = 0; mt < 16; ++mt) {
      const int dk0 = w * 256 + mt * 16 + hi * 4;
      s16x4 pk;
#pragma unroll
      for (int r = 0; r < 4; ++r) pk[r] = f2bf(S[mt][r]);
      *(s16x4*)((char*)SB + lo * 2048 + ((dk0 * 2) ^ swl)) = pk;
    }
    LGKM0();
    __builtin_amdgcn_s_barrier();   // bar4: new SB ready
  }
#undef WAITV4
#undef LGKM0
#undef CFENCE
#undef STAGE_KQ
#undef STAGE_KT
#undef RKQ
#undef RKT
#undef SBF
#undef RTF
#undef UTF
#undef LOAD_EXTRAS
}

// ---------------------------------------------------------------------------
// LayerNorm in place on out. One wave per row.
// ---------------------------------------------------------------------------
__global__ __launch_bounds__(256)
void ln_kernel(float* __restrict__ o, const float* __restrict__ gamma,
               const float* __restrict__ betap) {
  const int lane = threadIdx.x & 63;
  const int w = threadIdx.x >> 6;
  const size_t row = (size_t)blockIdx.x * 4 + w;
  float4 vals[4];
  float s = 0.f;
#pragma unroll
  for (int m = 0; m < 4; ++m) {
    vals[m] = *(const float4*)&o[row * D + m * 256 + lane * 4];
    s += (vals[m].x + vals[m].y) + (vals[m].z + vals[m].w);
  }
#pragma unroll
  for (int d = 1; d < 64; d <<= 1) s += __shfl_xor(s, d, 64);
  const float mu = s * (1.f / 1024.f);
  float vs = 0.f;
#pragma unroll
  for (int m = 0; m < 4; ++m) {
    float dx = vals[m].x - mu; vs += dx * dx;
    dx = vals[m].y - mu; vs += dx * dx;
    dx = vals[m].z - mu; vs += dx * dx;
    dx = vals[m].w - mu; vs += dx * dx;
  }
#pragma unroll
  for (int d = 1; d < 64; d <<= 1) vs += __shfl_xor(vs, d, 64);
  const float r = 1.f / sqrtf(vs * (1.f / 1024.f) + 1e-5f);
#pragma unroll
  for (int m = 0; m < 4; ++m) {
    const int dbase = m * 256 + lane * 4;
    float4 g4 = *(const float4*)&gamma[dbase];
    float4 b4 = *(const float4*)&betap[dbase];
    float4 y;
    y.x = (vals[m].x - mu) * r * g4.x + b4.x;
    y.y = (vals[m].y - mu) * r * g4.y + b4.y;
    y.z = (vals[m].z - mu) * r * g4.z + b4.z;
    y.w = (vals[m].w - mu) * r * g4.w + b4.w;
    *(float4*)&o[row * D + dbase] = y;
  }
}

// ---------------------------------------------------------------------------
extern "C" void kernel_launch(void* const* d_in, const int* in_sizes, int n_in,
                              void* d_out, int out_size, void* d_ws, size_t ws_size,
                              hipStream_t stream) {
  const float* x   = (const float*)d_in[0];
  const float* Wq  = (const float*)d_in[1];
  const float* Wk  = (const float*)d_in[2];
  const float* Wv  = (const float*)d_in[3];
  const float* Wb  = (const float*)d_in[4];
  const float* lng = (const float*)d_in[5];
  const float* lnb = (const float*)d_in[6];
  float* out = (float*)d_out;

  const size_t MB = 1ull << 20;
  char* wsb = (char*)d_ws;
  float* beta = (float*)wsb;                 // 64 KB
  short* Mg   = (short*)(wsb + 1 * MB);      // 2 MB
  short* Tg   = (short*)(wsb + 4 * MB);      // 2 MB
  short* WTq  = (short*)(wsb + 6 * MB);      // 2 MB
  short* WTk  = (short*)(wsb + 8 * MB);      // 2 MB
  short* WTv  = (short*)(wsb + 10 * MB);     // 2 MB
  short* xh   = (short*)(wsb + 16 * MB);     // 32 MB
  short* qh   = (short*)(wsb + 64 * MB);     // 32 MB
  short* kh   = (short*)(wsb + 96 * MB);
  short* vh   = (short*)(wsb + 128 * MB);
  short* kT   = (short*)(wsb + 160 * MB);

  const int N8 = (BATCH * LSEQ * D) / 8;
  const dim3 pg(128, 8);

  pack_bf16<<<2048, 256, 0, stream>>>(x, xh, N8);
  wtrans<<<dim3(16, 16), 256, 0, stream>>>(Wq, WTq);
  wtrans<<<dim3(16, 16), 256, 0, stream>>>(Wk, WTk);
  wtrans<<<dim3(16, 16), 256, 0, stream>>>(Wv, WTv);

  proj_mfma<<<pg, 256, 0, stream>>>(xh, WTq, qh, 0, 0.03125f);
  proj_mfma<<<pg, 256, 0, stream>>>(xh, WTk, kh, 1, 1.f);
  proj_mfma<<<pg, 256, 0, stream>>>(xh, WTv, vh, 2, 1.f);

  knormb<<<4096, 256, 0, stream>>>(kh);
  transpose_bf16<<<dim3(16, 32, 8), 256, 0, stream>>>(kh, kT);
  beta_kernel<<<4096, 256, 0, stream>>>(x, Wb, beta);

  precompute<<<256, 256, 0, stream>>>(qh, kh, beta, Mg, Tg);
  scan_chunked<<<dim3(8, 64), 256, 0, stream>>>(qh, kh, vh, kT, beta, Mg, Tg, out);
  ln_kernel<<<4096, 256, 0, stream>>>(out, lng, lnb);
}

// Round 9
// 673.006 us; speedup vs baseline: 1.9353x; 1.0447x over previous
//
#include <hip/hip_runtime.h>
#include <cstdint>
#include <cstddef>

#define D 1024
#define LSEQ 2048
#define BATCH 8
#define NCHUNK 32   // LSEQ / 64

typedef float fx4  __attribute__((ext_vector_type(4)));
typedef short s16x8 __attribute__((ext_vector_type(8)));
typedef short s16x4 __attribute__((ext_vector_type(4)));

static __device__ __forceinline__ short f2bf(float f) {
  unsigned u = __builtin_bit_cast(unsigned, f);
  u = (u + 0x7FFFu + ((u >> 16) & 1u)) >> 16;   // RNE (finite values)
  return (short)u;
}
static __device__ __forceinline__ float bf2f(unsigned short h) {
  unsigned u = ((unsigned)h) << 16;
  return __builtin_bit_cast(float, u);
}

// ---------------------------------------------------------------------------
// Fused: xh = bf16(x) AND beta = sigmoid(x . Wb). One wave per row.
// Beta accumulation order identical to the old beta_kernel (bit-identical).
// ---------------------------------------------------------------------------
__global__ __launch_bounds__(256)
void packbeta(const float* __restrict__ x, const float* __restrict__ Wb,
              short* __restrict__ xh, float* __restrict__ betao) {
  const int lane = threadIdx.x & 63;
  const int w = threadIdx.x >> 6;
  const size_t row = (size_t)blockIdx.x * 4 + w;
  float s = 0.f;
#pragma unroll
  for (int m = 0; m < 4; ++m) {
    float4 xv = *(const float4*)&x[row * D + m * 256 + lane * 4];
    float4 wv = *(const float4*)&Wb[m * 256 + lane * 4];
    s += xv.x * wv.x + xv.y * wv.y + xv.z * wv.z + xv.w * wv.w;
    s16x4 p;
    p[0] = f2bf(xv.x); p[1] = f2bf(xv.y); p[2] = f2bf(xv.z); p[3] = f2bf(xv.w);
    *(s16x4*)(xh + row * D + m * 256 + lane * 4) = p;
  }
#pragma unroll
  for (int d = 1; d < 64; d <<= 1) s += __shfl_xor(s, d, 64);
  if (lane == 0) betao[row] = 1.f / (1.f + expf(-s));
}

// ---------------------------------------------------------------------------
// W [K][N] fp32 -> WT [N][K] bf16, 64x64 tiles via LDS; z selects one of 3 W.
// ---------------------------------------------------------------------------
__global__ __launch_bounds__(256)
void wtrans3(const float* __restrict__ W0, const float* __restrict__ W1,
             const float* __restrict__ W2, short* __restrict__ WTb) {
  __shared__ short Tl[64][66];
  const float* W = blockIdx.z == 0 ? W0 : (blockIdx.z == 1 ? W1 : W2);
  short* WT = WTb + (size_t)blockIdx.z * D * D;
  const int nt = blockIdx.x, kt0 = blockIdx.y;
  const int tid = threadIdx.x;
  const int c = (tid & 15) * 4, r = tid >> 4;
#pragma unroll
  for (int p = 0; p < 4; ++p) {
    const int krow = r + p * 16;
    float4 v4 = *(const float4*)&W[(size_t)(kt0 * 64 + krow) * D + nt * 64 + c];
    Tl[c + 0][krow] = f2bf(v4.x);
    Tl[c + 1][krow] = f2bf(v4.y);
    Tl[c + 2][krow] = f2bf(v4.z);
    Tl[c + 3][krow] = f2bf(v4.w);
  }
  __syncthreads();
#pragma unroll
  for (int p = 0; p < 4; ++p) {
    const int n = r + p * 16;
    s16x4 o4;
#pragma unroll
    for (int j = 0; j < 4; ++j) o4[j] = Tl[n][c + j];
    *(s16x4*)(WT + (size_t)(nt * 64 + n) * D + kt0 * 64 + c) = o4;
  }
}

// ---------------------------------------------------------------------------
// bf16 MFMA projection GEMM, all three projections in one launch (z = 0/1/2
// = q/k/v). Same math as round-3 proj_mfma.
// ---------------------------------------------------------------------------
__global__ __launch_bounds__(256)
void proj_mfma3(const short* __restrict__ A, const short* __restrict__ WTb,
                short* __restrict__ OUTb) {
  __shared__ short As[2][4096];
  __shared__ short Bs[2][4096];
  const int z = blockIdx.z;
  const short* Bt = WTb + (size_t)z * D * D;
  short* OUT = OUTb + (size_t)z * ((size_t)BATCH * LSEQ * D);
  const int tid = threadIdx.x;
  const int l = tid & 63, w = tid >> 6;
  const int lo = l & 15, hi = l >> 4;
  const int wm = w >> 1, wn = w & 1;
  const int row0 = blockIdx.x * 128, col0 = blockIdx.y * 128;

#define STAGE(nb, ktn)                                                          \
  {                                                                             \
    const short* ga0 = A + ((size_t)(row0 + l) * D + (ktn) + w * 8);            \
    const short* gb0 = Bt + ((size_t)(col0 + l) * D + (ktn) + w * 8);           \
    __builtin_amdgcn_global_load_lds(                                           \
        (const __attribute__((address_space(1))) void*)ga0,                     \
        (__attribute__((address_space(3))) void*)&As[nb][(w * 128) * 8], 16, 0, 0); \
    __builtin_amdgcn_global_load_lds(                                           \
        (const __attribute__((address_space(1))) void*)(ga0 + 64 * D),          \
        (__attribute__((address_space(3))) void*)&As[nb][(w * 128 + 64) * 8], 16, 0, 0); \
    __builtin_amdgcn_global_load_lds(                                           \
        (const __attribute__((address_space(1))) void*)gb0,                     \
        (__attribute__((address_space(3))) void*)&Bs[nb][(w * 128) * 8], 16, 0, 0); \
    __builtin_amdgcn_global_load_lds(                                           \
        (const __attribute__((address_space(1))) void*)(gb0 + 64 * D),          \
        (__attribute__((address_space(3))) void*)&Bs[nb][(w * 128 + 64) * 8], 16, 0, 0); \
  }

  fx4 acc[4][4];
#pragma unroll
  for (int i = 0; i < 4; ++i)
#pragma unroll
    for (int j = 0; j < 4; ++j) acc[i][j] = (fx4){0.f, 0.f, 0.f, 0.f};

  STAGE(0, 0);
  __syncthreads();
  int cur = 0;
  for (int kt = 0; kt < D; kt += 32) {
    if (kt + 32 < D) STAGE(cur ^ 1, kt + 32);
    s16x8 af[4], bfr[4];
#pragma unroll
    for (int mt = 0; mt < 4; ++mt)
      af[mt] = *(const s16x8*)&As[cur][(hi * 128 + wm * 64 + mt * 16 + lo) * 8];
#pragma unroll
    for (int nt = 0; nt < 4; ++nt)
      bfr[nt] = *(const s16x8*)&Bs[cur][(hi * 128 + wn * 64 + nt * 16 + lo) * 8];
#pragma unroll
    for (int mt = 0; mt < 4; ++mt)
#pragma unroll
      for (int nt = 0; nt < 4; ++nt)
        acc[mt][nt] = __builtin_amdgcn_mfma_f32_16x16x32_bf16(af[mt], bfr[nt], acc[mt][nt], 0, 0, 0);
    __syncthreads();
    cur ^= 1;
  }
#undef STAGE

#pragma unroll
  for (int mt = 0; mt < 4; ++mt)
#pragma unroll
    for (int nt = 0; nt < 4; ++nt) {
      const size_t rbase = (size_t)(row0 + wm * 64 + mt * 16 + hi * 4);
      const int col = col0 + wn * 64 + nt * 16 + lo;
#pragma unroll
      for (int r = 0; r < 4; ++r) {
        float val = acc[mt][nt][r];
        if (z == 0) val *= 0.03125f;
        else if (z == 2) val = val / (1.f + expf(-val));
        OUT[(rbase + r) * D + col] = f2bf(val);
      }
    }
}

// ---------------------------------------------------------------------------
// k row L2-normalize, bf16 in place. One wave per row.
// ---------------------------------------------------------------------------
__global__ __launch_bounds__(256)
void knormb(short* __restrict__ kk) {
  const int lane = threadIdx.x & 63;
  const int w = threadIdx.x >> 6;
  const size_t row = (size_t)blockIdx.x * 4 + w;
  s16x8 v0 = *(const s16x8*)&kk[row * D + lane * 8];
  s16x8 v1 = *(const s16x8*)&kk[row * D + 512 + lane * 8];
  float f[16];
  float ss = 0.f;
#pragma unroll
  for (int j = 0; j < 8; ++j) {
    f[j] = bf2f((unsigned short)v0[j]);
    f[8 + j] = bf2f((unsigned short)v1[j]);
  }
#pragma unroll
  for (int j = 0; j < 16; ++j) ss += f[j] * f[j];
#pragma unroll
  for (int d = 1; d < 64; d <<= 1) ss += __shfl_xor(ss, d, 64);
  const float s = 1.f / fmaxf(sqrtf(ss), 1e-12f);
  s16x8 o0, o1;
#pragma unroll
  for (int j = 0; j < 8; ++j) {
    o0[j] = f2bf(f[j] * s);
    o1[j] = f2bf(f[8 + j] * s);
  }
  *(s16x8*)&kk[row * D + lane * 8] = o0;
  *(s16x8*)&kk[row * D + 512 + lane * 8] = o1;
}

// ---------------------------------------------------------------------------
// transpose kh [b][L][D] -> kT [b][D][L] (bf16), 64x64 tiles via LDS
// ---------------------------------------------------------------------------
__global__ __launch_bounds__(256)
void transpose_bf16(const short* __restrict__ kh, short* __restrict__ kT) {
  __shared__ short Tl[64][66];
  const int dt = blockIdx.x, lt = blockIdx.y, b = blockIdx.z;
  const int tid = threadIdx.x;
  const int c = (tid & 15) * 4, r = tid >> 4;
#pragma unroll
  for (int p = 0; p < 4; ++p) {
    const int row = r + p * 16;
    s16x4 v4 = *(const s16x4*)(kh + ((size_t)b * LSEQ + lt * 64 + row) * D + dt * 64 + c);
#pragma unroll
    for (int j = 0; j < 4; ++j) Tl[c + j][row] = v4[j];
  }
  __syncthreads();
#pragma unroll
  for (int p = 0; p < 4; ++p) {
    const int dk = r + p * 16;
    s16x4 o4;
#pragma unroll
    for (int j = 0; j < 4; ++j) o4[j] = Tl[dk][c + j];
    *(s16x4*)(kT + ((size_t)b * D + dt * 64 + dk) * LSEQ + lt * 64 + c) = o4;
  }
}

// ---------------------------------------------------------------------------
// Precompute per chunk (b,t): Minv and Tg (unchanged)
// ---------------------------------------------------------------------------
__global__ __launch_bounds__(256)
void precompute(const short* __restrict__ qh, const short* __restrict__ kh,
                const float* __restrict__ beta,
                short* __restrict__ Mg, short* __restrict__ Tg) {
  __shared__ float Ash[64 * 65];
  __shared__ float Msh[64 * 65];
  const int tid = threadIdx.x, l = tid & 63, w = tid >> 6;
  const int bt = blockIdx.x;
  const int b = bt >> 5, t = bt & 31;
  const int lo = l & 15, hi = l >> 4;
  const size_t rb = (size_t)b * LSEQ + t * 64;

  fx4 aK[4], aQ[4];
#pragma unroll
  for (int n = 0; n < 4; ++n) { aK[n] = (fx4){0,0,0,0}; aQ[n] = (fx4){0,0,0,0}; }

  const short* krow = kh + (rb + w * 16 + lo) * D;
  const short* qrow = qh + (rb + w * 16 + lo) * D;
#pragma unroll 2
  for (int ks = 0; ks < 32; ++ks) {
    s16x8 ak = *(const s16x8*)(krow + ks * 32 + hi * 8);
    s16x8 aq = *(const s16x8*)(qrow + ks * 32 + hi * 8);
#pragma unroll
    for (int n = 0; n < 4; ++n) {
      s16x8 bk = *(const s16x8*)(kh + (rb + n * 16 + lo) * D + ks * 32 + hi * 8);
      aK[n] = __builtin_amdgcn_mfma_f32_16x16x32_bf16(ak, bk, aK[n], 0, 0, 0);
      aQ[n] = __builtin_amdgcn_mfma_f32_16x16x32_bf16(aq, bk, aQ[n], 0, 0, 0);
    }
  }
#pragma unroll
  for (int n = 0; n < 4; ++n) {
#pragma unroll
    for (int r = 0; r < 4; ++r) {
      const int i = w * 16 + hi * 4 + r, s = n * 16 + lo;
      const float bi = beta[rb + i];
      Ash[i * 65 + s] = (s < i) ? bi * aK[n][r] : 0.f;
      Tg[(size_t)bt * 4096 + i * 64 + s] = (s <= i) ? f2bf(aQ[n][r]) : (short)0;
    }
  }
  __syncthreads();
  if (w == 0) {
    Msh[0 * 65 + l] = (l == 0) ? 1.f : 0.f;
    for (int i = 1; i < 64; ++i) {
      float s = 0.f;
      for (int ss = 0; ss < i; ++ss) s += Ash[i * 65 + ss] * Msh[ss * 65 + l];
      Msh[i * 65 + l] = ((i == l) ? 1.f : 0.f) - s;
    }
  }
  __syncthreads();
  {
    const int row = tid >> 2, c0 = (tid & 3) * 16;
    s16x8 o0, o1;
#pragma unroll
    for (int j = 0; j < 8; ++j) o0[j] = f2bf(Msh[row * 65 + c0 + j]);
#pragma unroll
    for (int j = 0; j < 8; ++j) o1[j] = f2bf(Msh[row * 65 + c0 + 8 + j]);
    *(s16x8*)(Mg + (size_t)bt * 4096 + row * 64 + c0) = o0;
    *(s16x8*)(Mg + (size_t)bt * 4096 + row * 64 + c0 + 8) = o1;
  }
}

// ---------------------------------------------------------------------------
// Sequential chunked scan, v7: 4-slot ring, 2KB slices, depth-3 lookahead.
// 48 uniform slices/chunk (16 K + 16 Q + 16 kT), slot = g%4 (48%4==0 so
// compile-time across chunks). Uniform s_waitcnt vmcnt(4): exactly slices
// g+1,g+2 (2 DMA each) are newer than slice g; in-order vmcnt retirement
// makes this invariant to extras/stores position. Last chunk stages clamped
// dummy slices so the counting never changes. Accumulation order identical
// to v6 (absmax must stay exactly 0.09985352).
// ---------------------------------------------------------------------------
__global__ __launch_bounds__(256, 2)
void scan_chunked(const short* __restrict__ qh, const short* __restrict__ kh,
                  const short* __restrict__ vh, const short* __restrict__ kT,
                  const float* __restrict__ beta,
                  const short* __restrict__ Mg, const short* __restrict__ Tg,
                  float* __restrict__ out) {
  __shared__ __align__(16) short SB[16 * 1024];      // 32 KB [n=16][dk] swizzled
  __shared__ __align__(16) short RTs[16 * 64];       // 2 KB rhs^T
  __shared__ __align__(16) short UTs[16 * 64];       // 2 KB U^T
  __shared__ __align__(1024) char RING[4][4][2048];  // 32 KB: 4 waves x 4 slots
  const int tid = threadIdx.x;
  const int l = tid & 63, w = tid >> 6;
  const int lo = l & 15, hi = l >> 4;
  const int b = blockIdx.x, n0 = blockIdx.y * 16;
  const size_t bL = (size_t)b * LSEQ;
  const int swl = (lo & 7) << 4;
  const int c0 = w * 16 + hi * 4;
  const int rsub = l >> 3;     // row-within-slice-half
  const int csub = l & 7;      // 16B group within row

#define WAITV4() asm volatile("s_waitcnt vmcnt(4)" ::: "memory")
#define LGKM0()  asm volatile("s_waitcnt lgkmcnt(0)" ::: "memory")

  // K/Q slice [16 rows x 64 dk] -> slot (linear LDS dst, XOR-preswizzled src)
#define STAGE_KQ(PTR, slot, rowbase, dk0)                                       \
  {                                                                             \
    _Pragma("unroll")                                                           \
    for (int ii = 0; ii < 2; ++ii) {                                            \
      const int rr_ = ii * 8 + rsub;                                            \
      const short* src_ = (PTR) + (bL + (size_t)((rowbase) + rr_)) * D + (dk0)  \
                          + 8 * (csub ^ (rr_ & 7));                             \
      __builtin_amdgcn_global_load_lds(                                         \
          (const __attribute__((address_space(1))) void*)src_,                  \
          (__attribute__((address_space(3))) void*)&RING[w][slot][ii * 1024],   \
          16, 0, 0);                                                            \
    }                                                                           \
  }

  // kT slice [16 dk x 64 c] -> slot
#define STAGE_KT(slot, dkbase, cb)                                              \
  {                                                                             \
    _Pragma("unroll")                                                           \
    for (int ii = 0; ii < 2; ++ii) {                                            \
      const int rr_ = ii * 8 + rsub;                                            \
      const short* src_ = kT + ((size_t)b * D + (dkbase) + rr_) * LSEQ + (cb)   \
                          + 8 * (csub ^ (rr_ & 7));                             \
      __builtin_amdgcn_global_load_lds(                                         \
          (const __attribute__((address_space(1))) void*)src_,                  \
          (__attribute__((address_space(3))) void*)&RING[w][slot][ii * 1024],   \
          16, 0, 0);                                                            \
    }                                                                           \
  }

#define RF(slot, j) \
  (*(const s16x8*)&RING[w][slot][lo * 128 + (((j) * 64 + hi * 16) ^ swl)])
#define SBF(byteoff) (*(const s16x8*)((const char*)SB + lo * 2048 + ((byteoff) ^ swl)))
#define RTF(ks) (*(const s16x8*)((const char*)RTs + lo * 128 + ((((ks) * 32 + hi * 8) * 2) ^ swl)))
#define UTF(ks) (*(const s16x8*)((const char*)UTs + lo * 128 + ((((ks) * 32 + hi * 8) * 2) ^ swl)))

  float vv[4], bb[4];
  s16x8 mg0, mg1, tg0, tg1;
#define LOAD_EXTRAS(tt)                                                         \
  {                                                                             \
    const int r0_ = (tt) * 64;                                                  \
    const size_t mtb_ = ((size_t)(b * NCHUNK + (tt))) * 4096 + (w * 16 + lo) * 64; \
    _Pragma("unroll")                                                           \
    for (int r = 0; r < 4; ++r) {                                               \
      vv[r] = bf2f((unsigned short)vh[(bL + r0_ + c0 + r) * D + n0 + lo]);      \
      bb[r] = beta[bL + r0_ + c0 + r];                                          \
    }                                                                           \
    mg0 = *(const s16x8*)(Mg + mtb_ + hi * 8);                                  \
    mg1 = *(const s16x8*)(Mg + mtb_ + 32 + hi * 8);                             \
    tg0 = *(const s16x8*)(Tg + mtb_ + hi * 8);                                  \
    tg1 = *(const s16x8*)(Tg + mtb_ + 32 + hi * 8);                             \
  }

  fx4 S[16];
#pragma unroll
  for (int mt = 0; mt < 16; ++mt) S[mt] = (fx4){0.f, 0.f, 0.f, 0.f};

  for (int i = tid; i < 16 * 1024 / 2; i += 256) ((int*)SB)[i] = 0;

  // prologue: extras first (older in vmcnt order), then slices 0,1,2 in flight
  LOAD_EXTRAS(0);
  asm volatile("" ::: "memory");
  STAGE_KQ(kh, 0, w * 16, 0);
  STAGE_KQ(kh, 1, w * 16, 64);
  STAGE_KQ(kh, 2, w * 16, 128);
  LGKM0();
  __builtin_amdgcn_s_barrier();   // SB zeros visible (no vmcnt drain)

  for (int t = 0; t < NCHUNK; ++t) {
    const int r0 = t * 64;
    const int rnext = (t + 1 < NCHUNK) ? (r0 + 64) : r0;  // clamped dummy tail

    // ---- P1: R = K_c @ S   (16 slices; stages K then Q)
    fx4 a0 = (fx4){0.f, 0.f, 0.f, 0.f}, a1 = (fx4){0.f, 0.f, 0.f, 0.f};
#pragma unroll
    for (int g = 0; g < 16; ++g) {
      WAITV4();
      s16x8 f0 = RF(g & 3, 0), f1 = RF(g & 3, 1);
      s16x8 b0 = SBF(g * 128 + hi * 16);
      s16x8 b1 = SBF(g * 128 + 64 + hi * 16);
      LGKM0();   // slot reads retired before re-stage
      if (g < 13) { STAGE_KQ(kh, (g + 3) & 3, r0 + w * 16, (g + 3) * 64); }
      else        { STAGE_KQ(qh, (g + 3) & 3, r0 + w * 16, (g - 13) * 64); }
      a0 = __builtin_amdgcn_mfma_f32_16x16x32_bf16(f0, b0, a0, 0, 0, 0);
      a1 = __builtin_amdgcn_mfma_f32_16x16x32_bf16(f1, b1, a1, 0, 0, 0);
    }
    {
      const fx4 acc = a0 + a1;
      s16x4 pk;
#pragma unroll
      for (int r = 0; r < 4; ++r) pk[r] = f2bf(bb[r] * (vv[r] - acc[r]));
      *(s16x4*)((char*)RTs + lo * 128 + ((c0 * 2) ^ swl)) = pk;
    }
    LGKM0();
    __builtin_amdgcn_s_barrier();   // bar1: RT ready

    // ---- P2: U = Minv @ rhs
    {
      fx4 u = (fx4){0.f, 0.f, 0.f, 0.f};
      u = __builtin_amdgcn_mfma_f32_16x16x32_bf16(mg0, RTF(0), u, 0, 0, 0);
      u = __builtin_amdgcn_mfma_f32_16x16x32_bf16(mg1, RTF(1), u, 0, 0, 0);
      s16x4 pk;
#pragma unroll
      for (int r = 0; r < 4; ++r) pk[r] = f2bf(u[r]);
      *(s16x4*)((char*)UTs + lo * 128 + ((c0 * 2) ^ swl)) = pk;
    }
    LGKM0();
    __builtin_amdgcn_s_barrier();   // bar2: UT ready

    const s16x8 bu0 = UTF(0), bu1 = UTF(1);

    // ---- P3: O = tril(QK^T) @ U + Q_c @ S(old)  (16 slices; stages Q then kT)
    {
      fx4 o = (fx4){0.f, 0.f, 0.f, 0.f};
      o = __builtin_amdgcn_mfma_f32_16x16x32_bf16(tg0, bu0, o, 0, 0, 0);
      o = __builtin_amdgcn_mfma_f32_16x16x32_bf16(tg1, bu1, o, 0, 0, 0);
      a0 = (fx4){0.f, 0.f, 0.f, 0.f};
#pragma unroll
      for (int g = 0; g < 16; ++g) {
        WAITV4();
        s16x8 f0 = RF(g & 3, 0), f1 = RF(g & 3, 1);
        s16x8 b0 = SBF(g * 128 + hi * 16);
        s16x8 b1 = SBF(g * 128 + 64 + hi * 16);
        LGKM0();
        if (g < 13) { STAGE_KQ(qh, (g + 3) & 3, r0 + w * 16, (g + 3) * 64); }
        else        { STAGE_KT((g + 3) & 3, w * 256 + (g - 13) * 16, r0); }
        o  = __builtin_amdgcn_mfma_f32_16x16x32_bf16(f0, b0, o, 0, 0, 0);
        a0 = __builtin_amdgcn_mfma_f32_16x16x32_bf16(f1, b1, a0, 0, 0, 0);
      }
      o = o + a0;
#pragma unroll
      for (int r = 0; r < 4; ++r)
        out[(bL + r0 + c0 + r) * D + n0 + lo] = o[r];
    }
    LGKM0();
    __builtin_amdgcn_s_barrier();   // bar3: all SB reads retired

    // extras for chunk t+1 (position-independent for wait safety; compiler
    // tracks their own vmcnt deps)
    {
      const int tn = (t + 1 < NCHUNK) ? (t + 1) : (NCHUNK - 1);
      LOAD_EXTRAS(tn);
    }

    // ---- P4: S += K_c^T @ U  (16 slices; stages kT then next-chunk K)
#pragma unroll
    for (int g = 0; g < 16; ++g) {
      WAITV4();
      s16x8 f0 = RF(g & 3, 0), f1 = RF(g & 3, 1);
      LGKM0();
      if (g < 13) { STAGE_KT((g + 3) & 3, w * 256 + (g + 3) * 16, r0); }
      else        { STAGE_KQ(kh, (g + 3) & 3, rnext + w * 16, (g - 13) * 64); }
      S[g] = __builtin_amdgcn_mfma_f32_16x16x32_bf16(f0, bu0, S[g], 0, 0, 0);
      S[g] = __builtin_amdgcn_mfma_f32_16x16x32_bf16(f1, bu1, S[g], 0, 0, 0);
    }

    // ---- P5: SB = bf16(S), own dk slice
#pragma unroll
    for (int mt = 0; mt < 16; ++mt) {
      const int dk0 = w * 256 + mt * 16 + hi * 4;
      s16x4 pk;
#pragma unroll
      for (int r = 0; r < 4; ++r) pk[r] = f2bf(S[mt][r]);
      *(s16x4*)((char*)SB + lo * 2048 + ((dk0 * 2) ^ swl)) = pk;
    }
    LGKM0();
    __builtin_amdgcn_s_barrier();   // bar4: new SB ready
  }
#undef WAITV4
#undef LGKM0
#undef STAGE_KQ
#undef STAGE_KT
#undef RF
#undef SBF
#undef RTF
#undef UTF
#undef LOAD_EXTRAS
}

// ---------------------------------------------------------------------------
// LayerNorm in place on out. One wave per row.
// ---------------------------------------------------------------------------
__global__ __launch_bounds__(256)
void ln_kernel(float* __restrict__ o, const float* __restrict__ gamma,
               const float* __restrict__ betap) {
  const int lane = threadIdx.x & 63;
  const int w = threadIdx.x >> 6;
  const size_t row = (size_t)blockIdx.x * 4 + w;
  float4 vals[4];
  float s = 0.f;
#pragma unroll
  for (int m = 0; m < 4; ++m) {
    vals[m] = *(const float4*)&o[row * D + m * 256 + lane * 4];
    s += (vals[m].x + vals[m].y) + (vals[m].z + vals[m].w);
  }
#pragma unroll
  for (int d = 1; d < 64; d <<= 1) s += __shfl_xor(s, d, 64);
  const float mu = s * (1.f / 1024.f);
  float vs = 0.f;
#pragma unroll
  for (int m = 0; m < 4; ++m) {
    float dx = vals[m].x - mu; vs += dx * dx;
    dx = vals[m].y - mu; vs += dx * dx;
    dx = vals[m].z - mu; vs += dx * dx;
    dx = vals[m].w - mu; vs += dx * dx;
  }
#pragma unroll
  for (int d = 1; d < 64; d <<= 1) vs += __shfl_xor(vs, d, 64);
  const float r = 1.f / sqrtf(vs * (1.f / 1024.f) + 1e-5f);
#pragma unroll
  for (int m = 0; m < 4; ++m) {
    const int dbase = m * 256 + lane * 4;
    float4 g4 = *(const float4*)&gamma[dbase];
    float4 b4 = *(const float4*)&betap[dbase];
    float4 y;
    y.x = (vals[m].x - mu) * r * g4.x + b4.x;
    y.y = (vals[m].y - mu) * r * g4.y + b4.y;
    y.z = (vals[m].z - mu) * r * g4.z + b4.z;
    y.w = (vals[m].w - mu) * r * g4.w + b4.w;
    *(float4*)&o[row * D + dbase] = y;
  }
}

// ---------------------------------------------------------------------------
extern "C" void kernel_launch(void* const* d_in, const int* in_sizes, int n_in,
                              void* d_out, int out_size, void* d_ws, size_t ws_size,
                              hipStream_t stream) {
  const float* x   = (const float*)d_in[0];
  const float* Wq  = (const float*)d_in[1];
  const float* Wk  = (const float*)d_in[2];
  const float* Wv  = (const float*)d_in[3];
  const float* Wb  = (const float*)d_in[4];
  const float* lng = (const float*)d_in[5];
  const float* lnb = (const float*)d_in[6];
  float* out = (float*)d_out;

  const size_t MB = 1ull << 20;
  char* wsb = (char*)d_ws;
  float* beta = (float*)wsb;                 // 64 KB
  short* Mg   = (short*)(wsb + 1 * MB);      // 2 MB
  short* Tg   = (short*)(wsb + 4 * MB);      // 2 MB
  short* WTq  = (short*)(wsb + 6 * MB);      // 3 x 2 MB contiguous (q,k,v)
  short* xh   = (short*)(wsb + 16 * MB);     // 32 MB
  short* qh   = (short*)(wsb + 64 * MB);     // 3 x 32 MB contiguous (q,k,v)
  short* kh   = (short*)(wsb + 96 * MB);
  short* vh   = (short*)(wsb + 128 * MB);
  short* kT   = (short*)(wsb + 160 * MB);

  packbeta<<<4096, 256, 0, stream>>>(x, Wb, xh, beta);
  wtrans3<<<dim3(16, 16, 3), 256, 0, stream>>>(Wq, Wk, Wv, WTq);
  proj_mfma3<<<dim3(128, 8, 3), 256, 0, stream>>>(xh, WTq, qh);
  knormb<<<4096, 256, 0, stream>>>(kh);
  transpose_bf16<<<dim3(16, 32, 8), 256, 0, stream>>>(kh, kT);
  precompute<<<256, 256, 0, stream>>>(qh, kh, beta, Mg, Tg);
  scan_chunked<<<dim3(8, 64), 256, 0, stream>>>(qh, kh, vh, kT, beta, Mg, Tg, out);
  ln_kernel<<<4096, 256, 0, stream>>>(out, lng, lnb);
}